// Round 6
// baseline (158.137 us; speedup 1.0000x reference)
//
#include <hip/hip_runtime.h>
#include <hip/hip_bf16.h>
#include <math.h>

#define NN   87
#define NN2  (NN * NN)        // 7569
#define SP   104              // W-panel / sD row stride (bf16)
#define PANEL (96 * SP)       // 9984 shorts per panel
#define NT   256

// ws layout (bytes)
#define WS_W    0                       // 2 panels bf16 W     : 39936 B
#define WS_E    (2 * PANEL * 2)         // last-batch E padded : 7632 f
#define WS_X    (WS_E + 7632 * 4)       // last-batch x padded : 7632 f
#define WS_LAM  (WS_X + 7632 * 4)       // last-batch evals    : 96 f
#define WS_NEED (WS_LAM + 96 * 4)

typedef __attribute__((ext_vector_type(8))) short bf16x8;
typedef __attribute__((ext_vector_type(4))) short bf16x4;
typedef __attribute__((ext_vector_type(4))) float f32x4;
typedef float f32x4u __attribute__((ext_vector_type(4), aligned(4)));

__device__ __forceinline__ short f2bf(float f) {
    __hip_bfloat16 h = __float2bfloat16(f);     // native cvt; compiler pk-fuses pairs
    return *(short*)&h;
}

__device__ __forceinline__ void ld8tail(const float* __restrict__ base, int off,
                                        bool scalarTail, float v[8]) {
    if (!scalarTail) {
        f32x4u a = *(const f32x4u*)(base + off);
        f32x4u b4 = *(const f32x4u*)(base + off + 4);
        v[0] = a.x; v[1] = a.y; v[2] = a.z; v[3] = a.w;
        v[4] = b4.x; v[5] = b4.y; v[6] = b4.z; v[7] = b4.w;
    } else {
        #pragma unroll
        for (int q = 0; q < 8; ++q) {
            int id = off + q;
            v[q] = base[(id < NN2) ? id : (NN2 - 1)];
        }
    }
}

__global__ void prep(const float* __restrict__ W, const float* __restrict__ evals,
                     const float* __restrict__ evecs, const float* __restrict__ x,
                     int B, char* __restrict__ ws)
{
    int idx = (int)blockIdx.x * NT + (int)threadIdx.x;
    short* wp = (short*)(ws + WS_W);
    float* ep = (float*)(ws + WS_E);
    float* xp = (float*)(ws + WS_X);
    float* lp = (float*)(ws + WS_LAM);

    if (idx < 2 * PANEL) {
        int p = idx / PANEL, rem = idx - p * PANEL;
        int r = rem / SP, c = rem - r * SP;
        short v = 0;
        if (r < NN && c < NN) v = f2bf(W[r * (2 * NN) + p * NN + c]);
        wp[idx] = v;
    }
    int i2 = idx - 2 * PANEL;
    if (i2 >= 0 && i2 < 7632) ep[i2] = (i2 < NN2) ? evecs[(size_t)(B - 1) * NN2 + i2] : 0.f;
    int i3 = i2 - 7632;
    if (i3 >= 0 && i3 < 7632) xp[i3] = (i3 < NN2) ? x[(size_t)(B - 1) * NN2 + i3] : 0.f;
    int i4 = i3 - 7632;
    if (i4 >= 0 && i4 < 96)   lp[i4] = (i4 < NN) ? evals[(size_t)(B - 1) * NN + i4] : 0.f;
}

template <bool WS>
__device__ __forceinline__ bf16x8 wload(const short* __restrict__ wp,
                                        const float* __restrict__ gW,
                                        int panel, int jrow, int jcl, int k0, bool tailKs)
{
    if constexpr (WS) {
        return *(const bf16x8*)&wp[panel * PANEL + jrow * SP + k0];
    } else {
        float v[8];
        if (!tailKs) {
            f32x4u a = *(const f32x4u*)(gW + jcl * (2 * NN) + panel * NN + k0);
            f32x4u b4 = *(const f32x4u*)(gW + jcl * (2 * NN) + panel * NN + k0 + 4);
            v[0] = a.x; v[1] = a.y; v[2] = a.z; v[3] = a.w;
            v[4] = b4.x; v[5] = b4.y; v[6] = b4.z; v[7] = b4.w;
        } else {
            #pragma unroll
            for (int q = 0; q < 8; ++q) {
                int k = k0 + q;
                v[q] = (k < NN) ? gW[jcl * (2 * NN) + panel * NN + k] : 0.f;
            }
        }
        bf16x8 o;
        #pragma unroll
        for (int q = 0; q < 8; ++q) o[q] = f2bf(v[q]);
        return o;
    }
}

template <bool WS>
__global__ __launch_bounds__(NT, 4)
void fused(const float* __restrict__ gx, const float* __restrict__ gevals,
           const float* __restrict__ gevecs, const float* __restrict__ dtime,
           const float* __restrict__ gW, const float* __restrict__ bias,
           const char* __restrict__ ws, int B, float* __restrict__ out)
{
    // union: sD (96x104 bf16 = 19968B) then sF (96x87 f32 packed = 33408B)
    __shared__ __align__(16) char uni[96 * NN * 4];
    short* const sD = (short*)uni;
    float* const sF = (float*)uni;

    const int b    = (int)blockIdx.x;
    const int tid  = (int)threadIdx.x;
    const int lane = tid & 63;
    const int wave = tid >> 6;
    const int l15  = lane & 15;
    const int lk   = lane >> 4;
    const int i0   = (wave >> 1) * 48;
    const int j0   = (wave & 1) * 48;
    const bool diag = (i0 == j0);

    const float* Eb   = gevecs + (size_t)b * NN2;
    const float* xb   = gx     + (size_t)b * NN2;
    const float* lamb = gevals + (size_t)b * NN;
    const short* wp = nullptr;
    if constexpr (WS) {
        wp = (const short*)(ws + WS_W);
        if (b == B - 1) {
            Eb   = (const float*)(ws + WS_E);
            xb   = (const float*)(ws + WS_X);
            lamb = (const float*)(ws + WS_LAM);
        }
    }
    const bool tailScalar = (!WS) && (b == B - 1);

    int ia[3], ja[3];
    float tr[3];
    #pragma unroll
    for (int r = 0; r < 3; ++r) {
        int i = i0 + 16 * r + l15;
        ia[r] = (i < NN) ? i : (NN - 1);
        tr[r] = fmaxf(dtime[ia[r]], 1e-8f);
        int j = j0 + 16 * r + l15;
        ja[r] = (j < NN) ? j : (NN - 1);
    }

    // ---------------- GEMM1: D = (E .* exp) @ E^T, swapped operands ----------------
    f32x4 acc1[3][3];
    #pragma unroll
    for (int c = 0; c < 3; ++c)
        #pragma unroll
        for (int r = 0; r < 3; ++r) acc1[c][r] = (f32x4){0.f, 0.f, 0.f, 0.f};

    #pragma unroll
    for (int ks = 0; ks < 3; ++ks) {
        const int k0 = ks * 32 + lk * 8;

        // lambda slice (masked for k>=87)
        float l8[8];
        if (ks < 2 || !tailScalar) {
            f32x4u a  = *(const f32x4u*)(lamb + k0);
            f32x4u c4 = *(const f32x4u*)(lamb + k0 + 4);
            l8[0] = a.x; l8[1] = a.y; l8[2] = a.z; l8[3] = a.w;
            l8[4] = c4.x; l8[5] = c4.y; l8[6] = c4.z; l8[7] = c4.w;
        } else {
            #pragma unroll
            for (int q = 0; q < 8; ++q) { int k = k0 + q; l8[q] = lamb[(k < NN) ? k : (NN - 1)]; }
        }
        if (ks == 2) {
            #pragma unroll
            for (int q = 0; q < 8; ++q)
                if (lk * 8 + q >= 23) l8[q] = 3e38f;   // k >= 87 -> exp -> 0
        }

        bf16x8 ef[3], af[3];
        float ve[3][8];
        #pragma unroll
        for (int c = 0; c < 3; ++c) {
            ld8tail(Eb, ja[c] * NN + k0, (ks == 2) && tailScalar, ve[c]);
            #pragma unroll
            for (int q = 0; q < 8; ++q) ef[c][q] = f2bf(ve[c][q]);
        }
        if (diag) {   // wave-uniform: i-rows == j-rows, reuse raw E values
            #pragma unroll
            for (int r = 0; r < 3; ++r)
                #pragma unroll
                for (int q = 0; q < 8; ++q)
                    af[r][q] = f2bf(ve[r][q] * __expf(-tr[r] * l8[q]));
        } else {
            #pragma unroll
            for (int r = 0; r < 3; ++r) {
                float va[8];
                ld8tail(Eb, ia[r] * NN + k0, (ks == 2) && tailScalar, va);
                #pragma unroll
                for (int q = 0; q < 8; ++q)
                    af[r][q] = f2bf(va[q] * __expf(-tr[r] * l8[q]));
            }
        }
        #pragma unroll
        for (int c = 0; c < 3; ++c)
            #pragma unroll
            for (int r = 0; r < 3; ++r)
                acc1[c][r] = __builtin_amdgcn_mfma_f32_16x16x32_bf16(ef[c], af[r], acc1[c][r], 0, 0, 0);
    }

    // store D -> sD: lane holds 4 consecutive j -> ds_write_b64
    #pragma unroll
    for (int c = 0; c < 3; ++c) {
        const int jb = j0 + 16 * c + lk * 4;
        #pragma unroll
        for (int r = 0; r < 3; ++r) {
            const int i = i0 + 16 * r + l15;
            bf16x4 v;
            #pragma unroll
            for (int q = 0; q < 4; ++q) v[q] = f2bf(acc1[c][r][q]);
            *(bf16x4*)&sD[i * SP + jb] = v;
        }
    }

    // ---------------- GEMM2 x-half (independent of sD, before barrier) ----------------
    f32x4 acc2[3][3];
    #pragma unroll
    for (int wr = 0; wr < 3; ++wr)
        #pragma unroll
        for (int xc = 0; xc < 3; ++xc) acc2[wr][xc] = (f32x4){0.f, 0.f, 0.f, 0.f};

    #pragma unroll
    for (int ks = 0; ks < 3; ++ks) {
        const int k0 = ks * 32 + lk * 8;
        bf16x8 wf[3], xf[3];
        #pragma unroll
        for (int wr = 0; wr < 3; ++wr)
            wf[wr] = wload<WS>(wp, gW, 0, j0 + 16 * wr + l15, ja[wr], k0, ks == 2);
        #pragma unroll
        for (int xc = 0; xc < 3; ++xc) {
            float v[8];
            ld8tail(xb, ia[xc] * NN + k0, (ks == 2) && tailScalar, v);
            #pragma unroll
            for (int q = 0; q < 8; ++q) xf[xc][q] = f2bf(v[q]);
        }
        #pragma unroll
        for (int wr = 0; wr < 3; ++wr)
            #pragma unroll
            for (int xc = 0; xc < 3; ++xc)
                acc2[wr][xc] = __builtin_amdgcn_mfma_f32_16x16x32_bf16(wf[wr], xf[xc], acc2[wr][xc], 0, 0, 0);
    }

    __syncthreads();   // barrier 1: sD ready

    // ---------------- GEMM2 D-half ----------------
    #pragma unroll
    for (int ks = 0; ks < 3; ++ks) {
        const int k0 = ks * 32 + lk * 8;
        bf16x8 wf[3], df[3];
        #pragma unroll
        for (int wr = 0; wr < 3; ++wr)
            wf[wr] = wload<WS>(wp, gW, 1, j0 + 16 * wr + l15, ja[wr], k0, ks == 2);
        #pragma unroll
        for (int xc = 0; xc < 3; ++xc)
            df[xc] = *(const bf16x8*)&sD[(i0 + 16 * xc + l15) * SP + k0];
        #pragma unroll
        for (int wr = 0; wr < 3; ++wr)
            #pragma unroll
            for (int xc = 0; xc < 3; ++xc)
                acc2[wr][xc] = __builtin_amdgcn_mfma_f32_16x16x32_bf16(wf[wr], df[xc], acc2[wr][xc], 0, 0, 0);
    }

    __syncthreads();   // barrier 2: all sD reads done before sF overwrite

    // ---------------- epilogue: pack out tile into sF (stride NN, packed) ----------------
    #pragma unroll
    for (int wr = 0; wr < 3; ++wr) {
        const int jb = j0 + 16 * wr + lk * 4;
        float bj[4];
        if (jb + 3 < NN) {
            f32x4u t = *(const f32x4u*)(bias + jb);
            bj[0] = t.x; bj[1] = t.y; bj[2] = t.z; bj[3] = t.w;
        } else {
            #pragma unroll
            for (int q = 0; q < 4; ++q) bj[q] = (jb + q < NN) ? bias[jb + q] : 0.f;
        }
        #pragma unroll
        for (int xc = 0; xc < 3; ++xc) {
            const int i = i0 + 16 * xc + l15;   // rows >=87 land in sF pad rows, never copied
            #pragma unroll
            for (int q = 0; q < 4; ++q) {
                const int j = jb + q;
                if (j < NN) sF[i * NN + j] = acc2[wr][xc][q] + bj[q];
            }
        }
    }

    __syncthreads();   // barrier 3: sF complete

    // ---------------- copy-out: contiguous, alignment-fixed dwordx4 ----------------
    {
        float* __restrict__ gb = out + (size_t)b * NN2;
        const int s = (4 - ((b * NN2) & 3)) & 3;          // shift to 16B-align global
        if (tid < s) gb[tid] = sF[tid];
        const int C = (NN2 - s) >> 2;
        for (int m = tid; m < C; m += NT) {
            const int n = s + 4 * m;
            f32x4 v;
            v.x = sF[n]; v.y = sF[n + 1]; v.z = sF[n + 2]; v.w = sF[n + 3];
            *(f32x4*)(gb + n) = v;
        }
        const int tl = s + 4 * C;
        if (tid < NN2 - tl) gb[tl + tid] = sF[tl + tid];
    }
}

extern "C" void kernel_launch(void* const* d_in, const int* in_sizes, int n_in,
                              void* d_out, int out_size, void* d_ws, size_t ws_size,
                              hipStream_t stream)
{
    const float* x     = (const float*)d_in[0];
    const float* evals = (const float*)d_in[1];
    const float* evecs = (const float*)d_in[2];
    const float* dtime = (const float*)d_in[3];
    const float* W     = (const float*)d_in[4];
    const float* bias  = (const float*)d_in[5];
    float* out = (float*)d_out;

    const int B = in_sizes[1] / NN;   // evals is (B, 87)

    if (ws_size >= (size_t)WS_NEED) {
        const int prep_elems = 2 * PANEL + 2 * 7632 + 96;
        prep<<<(prep_elems + NT - 1) / NT, NT, 0, stream>>>(W, evals, evecs, x, B, (char*)d_ws);
        fused<true><<<dim3(B), dim3(NT), 0, stream>>>(x, evals, evecs, dtime, W, bias,
                                                      (const char*)d_ws, B, out);
    } else {
        fused<false><<<dim3(B), dim3(NT), 0, stream>>>(x, evals, evecs, dtime, W, bias,
                                                       nullptr, B, out);
    }
}

// Round 7
// 142.875 us; speedup vs baseline: 1.1068x; 1.1068x over previous
//
#include <hip/hip_runtime.h>
#include <hip/hip_bf16.h>
#include <math.h>

#define NN   87
#define NN2  (NN * NN)        // 7569
#define SP   104              // W-panel / sD row stride (bf16)
#define PANEL (96 * SP)       // 9984 shorts per panel
#define NT   256

// ws layout (bytes)
#define WS_W    0                       // 2 panels bf16 W     : 39936 B
#define WS_E    (2 * PANEL * 2)         // last-batch E padded : 7632 f
#define WS_X    (WS_E + 7632 * 4)       // last-batch x padded : 7632 f
#define WS_LAM  (WS_X + 7632 * 4)       // last-batch evals    : 96 f
#define WS_NEED (WS_LAM + 96 * 4)

typedef __attribute__((ext_vector_type(8))) short bf16x8;
typedef __attribute__((ext_vector_type(4))) short bf16x4;
typedef __attribute__((ext_vector_type(4))) float f32x4;
typedef float f32x4u __attribute__((ext_vector_type(4), aligned(4)));

__device__ __forceinline__ short f2bf(float f) {
    __hip_bfloat16 h = __float2bfloat16(f);     // native cvt; compiler pk-fuses pairs
    return *(short*)&h;
}

__device__ __forceinline__ void ld8tail(const float* __restrict__ base, int off,
                                        bool scalarTail, float v[8]) {
    if (!scalarTail) {
        f32x4u a = *(const f32x4u*)(base + off);
        f32x4u b4 = *(const f32x4u*)(base + off + 4);
        v[0] = a.x; v[1] = a.y; v[2] = a.z; v[3] = a.w;
        v[4] = b4.x; v[5] = b4.y; v[6] = b4.z; v[7] = b4.w;
    } else {
        #pragma unroll
        for (int q = 0; q < 8; ++q) {
            int id = off + q;
            v[q] = base[(id < NN2) ? id : (NN2 - 1)];
        }
    }
}

__global__ void prep(const float* __restrict__ W, const float* __restrict__ evals,
                     const float* __restrict__ evecs, const float* __restrict__ x,
                     int B, char* __restrict__ ws)
{
    int idx = (int)blockIdx.x * NT + (int)threadIdx.x;
    short* wp = (short*)(ws + WS_W);
    float* ep = (float*)(ws + WS_E);
    float* xp = (float*)(ws + WS_X);
    float* lp = (float*)(ws + WS_LAM);

    if (idx < 2 * PANEL) {
        int p = idx / PANEL, rem = idx - p * PANEL;
        int r = rem / SP, c = rem - r * SP;
        short v = 0;
        if (r < NN && c < NN) v = f2bf(W[r * (2 * NN) + p * NN + c]);
        wp[idx] = v;
    }
    int i2 = idx - 2 * PANEL;
    if (i2 >= 0 && i2 < 7632) ep[i2] = (i2 < NN2) ? evecs[(size_t)(B - 1) * NN2 + i2] : 0.f;
    int i3 = i2 - 7632;
    if (i3 >= 0 && i3 < 7632) xp[i3] = (i3 < NN2) ? x[(size_t)(B - 1) * NN2 + i3] : 0.f;
    int i4 = i3 - 7632;
    if (i4 >= 0 && i4 < 96)   lp[i4] = (i4 < NN) ? evals[(size_t)(B - 1) * NN + i4] : 0.f;
}

template <bool WS>
__device__ __forceinline__ bf16x8 wload(const short* __restrict__ wp,
                                        const float* __restrict__ gW,
                                        int panel, int jrow, int jcl, int k0, bool tailKs)
{
    if constexpr (WS) {
        return *(const bf16x8*)&wp[panel * PANEL + jrow * SP + k0];
    } else {
        float v[8];
        if (!tailKs) {
            f32x4u a = *(const f32x4u*)(gW + jcl * (2 * NN) + panel * NN + k0);
            f32x4u b4 = *(const f32x4u*)(gW + jcl * (2 * NN) + panel * NN + k0 + 4);
            v[0] = a.x; v[1] = a.y; v[2] = a.z; v[3] = a.w;
            v[4] = b4.x; v[5] = b4.y; v[6] = b4.z; v[7] = b4.w;
        } else {
            #pragma unroll
            for (int q = 0; q < 8; ++q) {
                int k = k0 + q;
                v[q] = (k < NN) ? gW[jcl * (2 * NN) + panel * NN + k] : 0.f;
            }
        }
        bf16x8 o;
        #pragma unroll
        for (int q = 0; q < 8; ++q) o[q] = f2bf(v[q]);
        return o;
    }
}

template <bool WS>
__global__ __launch_bounds__(NT, 4)
void fused(const float* __restrict__ gx, const float* __restrict__ gevals,
           const float* __restrict__ gevecs, const float* __restrict__ dtime,
           const float* __restrict__ gW, const float* __restrict__ bias,
           const char* __restrict__ ws, int B, float* __restrict__ out)
{
    // union: sD (96x104 bf16 = 19968B) then sF (96x87 f32 packed = 33408B)
    __shared__ __align__(16) char uni[96 * NN * 4];
    short* const sD = (short*)uni;
    float* const sF = (float*)uni;

    const int b    = (int)blockIdx.x;
    const int tid  = (int)threadIdx.x;
    const int lane = tid & 63;
    const int wave = tid >> 6;
    const int l15  = lane & 15;
    const int lk   = lane >> 4;
    const int i0   = (wave >> 1) * 48;
    const int j0   = (wave & 1) * 48;

    const float* Eb   = gevecs + (size_t)b * NN2;
    const float* xb   = gx     + (size_t)b * NN2;
    const float* lamb = gevals + (size_t)b * NN;
    const short* wp = nullptr;
    if constexpr (WS) {
        wp = (const short*)(ws + WS_W);
        if (b == B - 1) {
            Eb   = (const float*)(ws + WS_E);
            xb   = (const float*)(ws + WS_X);
            lamb = (const float*)(ws + WS_LAM);
        }
    }
    const bool tailScalar = (!WS) && (b == B - 1);

    int ia[3], ja[3];
    float tr[3];
    #pragma unroll
    for (int r = 0; r < 3; ++r) {
        int i = i0 + 16 * r + l15;
        ia[r] = (i < NN) ? i : (NN - 1);
        tr[r] = fmaxf(dtime[ia[r]], 1e-8f);
        int j = j0 + 16 * r + l15;
        ja[r] = (j < NN) ? j : (NN - 1);
    }

    // ---------------- GEMM1: D = (E .* exp) @ E^T, swapped operands ----------------
    {
        f32x4 acc1[3][3];
        #pragma unroll
        for (int c = 0; c < 3; ++c)
            #pragma unroll
            for (int r = 0; r < 3; ++r) acc1[c][r] = (f32x4){0.f, 0.f, 0.f, 0.f};

        #pragma unroll
        for (int ks = 0; ks < 3; ++ks) {
            const int k0 = ks * 32 + lk * 8;

            // lambda slice (masked for k>=87)
            float l8[8];
            if (ks < 2 || !tailScalar) {
                f32x4u a  = *(const f32x4u*)(lamb + k0);
                f32x4u c4 = *(const f32x4u*)(lamb + k0 + 4);
                l8[0] = a.x; l8[1] = a.y; l8[2] = a.z; l8[3] = a.w;
                l8[4] = c4.x; l8[5] = c4.y; l8[6] = c4.z; l8[7] = c4.w;
            } else {
                #pragma unroll
                for (int q = 0; q < 8; ++q) { int k = k0 + q; l8[q] = lamb[(k < NN) ? k : (NN - 1)]; }
            }
            if (ks == 2) {
                #pragma unroll
                for (int q = 0; q < 8; ++q)
                    if (lk * 8 + q >= 23) l8[q] = 3e38f;   // k >= 87 -> exp -> 0
            }

            bf16x8 ef[3], af[3];
            #pragma unroll
            for (int c = 0; c < 3; ++c) {
                float v[8];
                ld8tail(Eb, ja[c] * NN + k0, (ks == 2) && tailScalar, v);
                #pragma unroll
                for (int q = 0; q < 8; ++q) ef[c][q] = f2bf(v[q]);
            }
            #pragma unroll
            for (int r = 0; r < 3; ++r) {
                float va[8];
                ld8tail(Eb, ia[r] * NN + k0, (ks == 2) && tailScalar, va);
                #pragma unroll
                for (int q = 0; q < 8; ++q)
                    af[r][q] = f2bf(va[q] * __expf(-tr[r] * l8[q]));
            }
            #pragma unroll
            for (int c = 0; c < 3; ++c)
                #pragma unroll
                for (int r = 0; r < 3; ++r)
                    acc1[c][r] = __builtin_amdgcn_mfma_f32_16x16x32_bf16(ef[c], af[r], acc1[c][r], 0, 0, 0);
        }

        // store D -> sD: lane holds 4 consecutive j -> ds_write_b64
        #pragma unroll
        for (int c = 0; c < 3; ++c) {
            const int jb = j0 + 16 * c + lk * 4;
            #pragma unroll
            for (int r = 0; r < 3; ++r) {
                const int i = i0 + 16 * r + l15;
                bf16x4 v;
                #pragma unroll
                for (int q = 0; q < 4; ++q) v[q] = f2bf(acc1[c][r][q]);
                *(bf16x4*)&sD[i * SP + jb] = v;
            }
        }
    }
    // Hard scheduling fence: acc1's last use (sD stores) must complete here so
    // acc1's AGPRs are dead before acc2 is born -> peak AGPR demand stays ~36.
    __builtin_amdgcn_sched_barrier(0);

    // ---------------- GEMM2 x-half (independent of sD, before barrier) ----------------
    f32x4 acc2[3][3];
    #pragma unroll
    for (int wr = 0; wr < 3; ++wr)
        #pragma unroll
        for (int xc = 0; xc < 3; ++xc) acc2[wr][xc] = (f32x4){0.f, 0.f, 0.f, 0.f};

    #pragma unroll
    for (int ks = 0; ks < 3; ++ks) {
        const int k0 = ks * 32 + lk * 8;
        bf16x8 wf[3], xf[3];
        #pragma unroll
        for (int wr = 0; wr < 3; ++wr)
            wf[wr] = wload<WS>(wp, gW, 0, j0 + 16 * wr + l15, ja[wr], k0, ks == 2);
        #pragma unroll
        for (int xc = 0; xc < 3; ++xc) {
            float v[8];
            ld8tail(xb, ia[xc] * NN + k0, (ks == 2) && tailScalar, v);
            #pragma unroll
            for (int q = 0; q < 8; ++q) xf[xc][q] = f2bf(v[q]);
        }
        #pragma unroll
        for (int wr = 0; wr < 3; ++wr)
            #pragma unroll
            for (int xc = 0; xc < 3; ++xc)
                acc2[wr][xc] = __builtin_amdgcn_mfma_f32_16x16x32_bf16(wf[wr], xf[xc], acc2[wr][xc], 0, 0, 0);
    }

    __syncthreads();   // barrier 1: sD ready

    // ---------------- GEMM2 D-half ----------------
    #pragma unroll
    for (int ks = 0; ks < 3; ++ks) {
        const int k0 = ks * 32 + lk * 8;
        bf16x8 wf[3], df[3];
        #pragma unroll
        for (int wr = 0; wr < 3; ++wr)
            wf[wr] = wload<WS>(wp, gW, 1, j0 + 16 * wr + l15, ja[wr], k0, ks == 2);
        #pragma unroll
        for (int xc = 0; xc < 3; ++xc)
            df[xc] = *(const bf16x8*)&sD[(i0 + 16 * xc + l15) * SP + k0];
        #pragma unroll
        for (int wr = 0; wr < 3; ++wr)
            #pragma unroll
            for (int xc = 0; xc < 3; ++xc)
                acc2[wr][xc] = __builtin_amdgcn_mfma_f32_16x16x32_bf16(wf[wr], df[xc], acc2[wr][xc], 0, 0, 0);
    }

    __syncthreads();   // barrier 2: all sD reads done before sF overwrite

    // ---------------- epilogue: pack out tile into sF (stride NN, packed) ----------------
    #pragma unroll
    for (int wr = 0; wr < 3; ++wr) {
        const int jb = j0 + 16 * wr + lk * 4;
        float bj[4];
        if (jb + 3 < NN) {
            f32x4u t = *(const f32x4u*)(bias + jb);
            bj[0] = t.x; bj[1] = t.y; bj[2] = t.z; bj[3] = t.w;
        } else {
            #pragma unroll
            for (int q = 0; q < 4; ++q) bj[q] = (jb + q < NN) ? bias[jb + q] : 0.f;
        }
        #pragma unroll
        for (int xc = 0; xc < 3; ++xc) {
            const int i = i0 + 16 * xc + l15;   // rows >=87 land in sF pad rows, never copied
            #pragma unroll
            for (int q = 0; q < 4; ++q) {
                const int j = jb + q;
                if (j < NN) sF[i * NN + j] = acc2[wr][xc][q] + bj[q];
            }
        }
    }

    __syncthreads();   // barrier 3: sF complete

    // ---------------- copy-out: contiguous, alignment-fixed dwordx4 ----------------
    {
        float* __restrict__ gb = out + (size_t)b * NN2;
        const int s = (4 - ((b * NN2) & 3)) & 3;          // shift to 16B-align global
        if (tid < s) gb[tid] = sF[tid];
        const int C = (NN2 - s) >> 2;
        for (int m = tid; m < C; m += NT) {
            const int n = s + 4 * m;
            f32x4 v;
            v.x = sF[n]; v.y = sF[n + 1]; v.z = sF[n + 2]; v.w = sF[n + 3];
            *(f32x4*)(gb + n) = v;
        }
        const int tl = s + 4 * C;
        if (tid < NN2 - tl) gb[tl + tid] = sF[tl + tid];
    }
}

extern "C" void kernel_launch(void* const* d_in, const int* in_sizes, int n_in,
                              void* d_out, int out_size, void* d_ws, size_t ws_size,
                              hipStream_t stream)
{
    const float* x     = (const float*)d_in[0];
    const float* evals = (const float*)d_in[1];
    const float* evecs = (const float*)d_in[2];
    const float* dtime = (const float*)d_in[3];
    const float* W     = (const float*)d_in[4];
    const float* bias  = (const float*)d_in[5];
    float* out = (float*)d_out;

    const int B = in_sizes[1] / NN;   // evals is (B, 87)

    if (ws_size >= (size_t)WS_NEED) {
        const int prep_elems = 2 * PANEL + 2 * 7632 + 96;
        prep<<<(prep_elems + NT - 1) / NT, NT, 0, stream>>>(W, evals, evecs, x, B, (char*)d_ws);
        fused<true><<<dim3(B), dim3(NT), 0, stream>>>(x, evals, evecs, dtime, W, bias,
                                                      (const char*)d_ws, B, out);
    } else {
        fused<false><<<dim3(B), dim3(NT), 0, stream>>>(x, evals, evecs, dtime, W, bias,
                                                       nullptr, B, out);
    }
}

// Round 8
// 103.055 us; speedup vs baseline: 1.5345x; 1.3864x over previous
//
#include <hip/hip_runtime.h>
#include <hip/hip_bf16.h>
#include <math.h>

#define NN    87
#define NN2   (NN * NN)       // 7569
#define SPH   104             // panel row stride in shorts (208 B)
#define RP    96
#define PANEL (RP * SPH)      // 9984 shorts = 19968 B per panel
#define NT    256

// ws: only the two bf16 W panels
#define WS_NEED (2 * PANEL * 2)

typedef __attribute__((ext_vector_type(8))) short bf16x8;
typedef __attribute__((ext_vector_type(4))) short bf16x4;
typedef __attribute__((ext_vector_type(4))) float f32x4;
typedef float f32x4u __attribute__((ext_vector_type(4), aligned(4)));

__device__ __forceinline__ short f2bf(float f) {
    __hip_bfloat16 h = __float2bfloat16(f);
    return *(short*)&h;
}
__device__ __forceinline__ float bf2f(short s) {
    union { unsigned u; float f; } v;
    v.u = ((unsigned)(unsigned short)s) << 16;
    return v.f;
}

// W (87 x 174 fp32) -> two zero-padded bf16 panels [96][104]
__global__ void prep(const float* __restrict__ W, short* __restrict__ wp) {
    int idx = (int)blockIdx.x * NT + (int)threadIdx.x;
    if (idx >= 2 * PANEL) return;
    int p = idx / PANEL, rem = idx - p * PANEL;
    int r = rem / SPH, c = rem - r * SPH;
    short v = 0;
    if (r < NN && c < NN) v = f2bf(W[r * (2 * NN) + p * NN + c]);
    wp[idx] = v;
}

// W fragment: bf16 panel in ws (WS) or fp32 W + cvt + tail mask (!WS)
template <bool WS>
__device__ __forceinline__ bf16x8 wload(const short* __restrict__ wp,
                                        const float* __restrict__ gW,
                                        int panel, int jrow, int jcl, int k0, bool tailKs)
{
    if constexpr (WS) {
        return *(const bf16x8*)&wp[panel * PANEL + jrow * SPH + k0];
    } else {
        float v[8];
        if (!tailKs) {
            f32x4u a  = *(const f32x4u*)(gW + jcl * (2 * NN) + panel * NN + k0);
            f32x4u b4 = *(const f32x4u*)(gW + jcl * (2 * NN) + panel * NN + k0 + 4);
            v[0] = a.x; v[1] = a.y; v[2] = a.z; v[3] = a.w;
            v[4] = b4.x; v[5] = b4.y; v[6] = b4.z; v[7] = b4.w;
        } else {
            #pragma unroll
            for (int q = 0; q < 8; ++q) {
                int k = k0 + q;
                v[q] = (k < NN) ? gW[jcl * (2 * NN) + panel * NN + k] : 0.f;
            }
        }
        bf16x8 o;
        #pragma unroll
        for (int q = 0; q < 8; ++q) o[q] = f2bf(v[q]);
        return o;
    }
}

template <bool WS>
__global__ __launch_bounds__(NT, 4)
void fused(const float* __restrict__ gx, const float* __restrict__ gevals,
           const float* __restrict__ gevecs, const float* __restrict__ dtime,
           const float* __restrict__ gW, const float* __restrict__ bias,
           const short* __restrict__ wp, float* __restrict__ out)
{
    // smem regions (39936 B):
    //   phase 1: sE [96][104] bf16  |  sX [96][104] bf16
    //   phase 2: sD [96][104] bf16 (over sE)  |  sX still live
    //   phase 3: sF [96][87] fp32 (over sE+part of sX)
    __shared__ __align__(16) char smem[2 * PANEL * 2];
    short* const sE = (short*)smem;
    short* const sX = (short*)(smem + PANEL * 2);
    short* const sD = (short*)smem;
    float* const sF = (float*)smem;
    __shared__ float sLam[RP];

    const int b    = (int)blockIdx.x;
    const int tid  = (int)threadIdx.x;
    const int lane = tid & 63;
    const int wave = tid >> 6;
    const int l15  = lane & 15;
    const int lk   = lane >> 4;
    const int i0   = (wave >> 1) * 48;
    const int j0   = (wave & 1) * 48;

    const float* __restrict__ Eb   = gevecs + (size_t)b * NN2;
    const float* __restrict__ xb   = gx     + (size_t)b * NN2;
    const float* __restrict__ lamb = gevals + (size_t)b * NN;

    // ---------------- stage lambda (zero-padded) ----------------
    if (tid < RP) sLam[tid] = (tid < NN) ? lamb[tid] : 0.f;

    // ---------------- stage E, x as bf16 panels (streamed, independent) ----------------
    for (int u = tid; u < NN * 22; u += NT) {
        int r = u / 22, sg = u - r * 22, c = sg * 4;
        const float* pE = Eb + r * NN + c;
        const float* pX = xb + r * NN + c;
        float e0, e1, e2, e3, x0, x1, x2, x3;
        if (sg < 21) {
            f32x4u te = *(const f32x4u*)pE; e0 = te.x; e1 = te.y; e2 = te.z; e3 = te.w;
            f32x4u tx = *(const f32x4u*)pX; x0 = tx.x; x1 = tx.y; x2 = tx.z; x3 = tx.w;
        } else {   // cols 84..86 + zero col 87; never reads out of bounds
            e0 = pE[0]; e1 = pE[1]; e2 = pE[2]; e3 = 0.f;
            x0 = pX[0]; x1 = pX[1]; x2 = pX[2]; x3 = 0.f;
        }
        bf16x4 we = {f2bf(e0), f2bf(e1), f2bf(e2), f2bf(e3)};
        bf16x4 wx = {f2bf(x0), f2bf(x1), f2bf(x2), f2bf(x3)};
        *(bf16x4*)&sE[r * SPH + c] = we;
        *(bf16x4*)&sX[r * SPH + c] = wx;
    }
    {
        const bf16x4 z = {0, 0, 0, 0};
        for (int u = tid; u < 9 * 26; u += NT) {      // rows 87..95, all cols
            int r = NN + u / 26, c = (u % 26) * 4;
            *(bf16x4*)&sE[r * SPH + c] = z;
            *(bf16x4*)&sX[r * SPH + c] = z;
        }
        for (int u = tid; u < NN * 4; u += NT) {      // rows 0..86, cols 88..103
            int r = u >> 2, c = 88 + (u & 3) * 4;
            *(bf16x4*)&sE[r * SPH + c] = z;
            *(bf16x4*)&sX[r * SPH + c] = z;
        }
    }
    __syncthreads();   // B1: panels ready

    int ir[3], jr[3];
    float tr_[3];
    #pragma unroll
    for (int r = 0; r < 3; ++r) {
        ir[r] = i0 + 16 * r + l15;
        jr[r] = j0 + 16 * r + l15;
        tr_[r] = fmaxf(dtime[ir[r] < NN ? ir[r] : NN - 1], 1e-8f);
    }

    // ---------------- GEMM1: D = (E .* exp(-t_i lam_k)) @ E^T (from LDS) ----------------
    f32x4 acc1[3][3];
    #pragma unroll
    for (int c = 0; c < 3; ++c)
        #pragma unroll
        for (int r = 0; r < 3; ++r) acc1[c][r] = (f32x4){0.f, 0.f, 0.f, 0.f};

    #pragma unroll
    for (int ks = 0; ks < 3; ++ks) {
        const int k0 = ks * 32 + lk * 8;
        f32x4 la  = *(const f32x4*)&sLam[k0];
        f32x4 lb4 = *(const f32x4*)&sLam[k0 + 4];
        float l8_[8] = {la.x, la.y, la.z, la.w, lb4.x, lb4.y, lb4.z, lb4.w};

        bf16x8 ef[3], af[3];
        #pragma unroll
        for (int c = 0; c < 3; ++c) {
            bf16x4 lo = *(const bf16x4*)&sE[jr[c] * SPH + k0];
            bf16x4 hi = *(const bf16x4*)&sE[jr[c] * SPH + k0 + 4];
            #pragma unroll
            for (int q = 0; q < 4; ++q) { ef[c][q] = lo[q]; ef[c][q + 4] = hi[q]; }
        }
        #pragma unroll
        for (int r = 0; r < 3; ++r) {
            bf16x4 lo = *(const bf16x4*)&sE[ir[r] * SPH + k0];
            bf16x4 hi = *(const bf16x4*)&sE[ir[r] * SPH + k0 + 4];
            #pragma unroll
            for (int q = 0; q < 4; ++q) {
                af[r][q]     = f2bf(bf2f(lo[q]) * __expf(-tr_[r] * l8_[q]));
                af[r][q + 4] = f2bf(bf2f(hi[q]) * __expf(-tr_[r] * l8_[q + 4]));
            }
        }
        #pragma unroll
        for (int c = 0; c < 3; ++c)
            #pragma unroll
            for (int r = 0; r < 3; ++r)
                acc1[c][r] = __builtin_amdgcn_mfma_f32_16x16x32_bf16(ef[c], af[r], acc1[c][r], 0, 0, 0);
    }
    __syncthreads();   // B2: all sE reads done -> region reusable for D

    // ---------------- D -> sD (bf16, b64 stores; rows/cols >=87 are true zeros) ----------------
    #pragma unroll
    for (int c = 0; c < 3; ++c) {
        const int jb = j0 + 16 * c + lk * 4;
        #pragma unroll
        for (int r = 0; r < 3; ++r) {
            const int i = i0 + 16 * r + l15;
            bf16x4 v = {f2bf(acc1[c][r][0]), f2bf(acc1[c][r][1]),
                        f2bf(acc1[c][r][2]), f2bf(acc1[c][r][3])};
            *(bf16x4*)&sD[i * SPH + jb] = v;
        }
    }
    __builtin_amdgcn_sched_barrier(0);   // acc1 dead before acc2 is born

    // ---------------- GEMM2 x-half (reads sX + global W; overlaps D-write drain) ----------------
    f32x4 acc2[3][3];
    #pragma unroll
    for (int wr = 0; wr < 3; ++wr)
        #pragma unroll
        for (int xc = 0; xc < 3; ++xc) acc2[wr][xc] = (f32x4){0.f, 0.f, 0.f, 0.f};

    #pragma unroll
    for (int ks = 0; ks < 3; ++ks) {
        const int k0 = ks * 32 + lk * 8;
        bf16x8 wf[3], xf[3];
        #pragma unroll
        for (int wr = 0; wr < 3; ++wr) {
            int jc = jr[wr] < NN ? jr[wr] : NN - 1;
            wf[wr] = wload<WS>(wp, gW, 0, jr[wr], jc, k0, ks == 2);
        }
        #pragma unroll
        for (int xc = 0; xc < 3; ++xc) {
            bf16x4 lo = *(const bf16x4*)&sX[ir[xc] * SPH + k0];
            bf16x4 hi = *(const bf16x4*)&sX[ir[xc] * SPH + k0 + 4];
            #pragma unroll
            for (int q = 0; q < 4; ++q) { xf[xc][q] = lo[q]; xf[xc][q + 4] = hi[q]; }
        }
        #pragma unroll
        for (int wr = 0; wr < 3; ++wr)
            #pragma unroll
            for (int xc = 0; xc < 3; ++xc)
                acc2[wr][xc] = __builtin_amdgcn_mfma_f32_16x16x32_bf16(wf[wr], xf[xc], acc2[wr][xc], 0, 0, 0);
    }
    __syncthreads();   // B3: all D writes visible

    // ---------------- GEMM2 D-half ----------------
    #pragma unroll
    for (int ks = 0; ks < 3; ++ks) {
        const int k0 = ks * 32 + lk * 8;
        bf16x8 wf[3], df[3];
        #pragma unroll
        for (int wr = 0; wr < 3; ++wr) {
            int jc = jr[wr] < NN ? jr[wr] : NN - 1;
            wf[wr] = wload<WS>(wp, gW, 1, jr[wr], jc, k0, ks == 2);
        }
        #pragma unroll
        for (int xc = 0; xc < 3; ++xc) {
            bf16x4 lo = *(const bf16x4*)&sD[ir[xc] * SPH + k0];
            bf16x4 hi = *(const bf16x4*)&sD[ir[xc] * SPH + k0 + 4];
            #pragma unroll
            for (int q = 0; q < 4; ++q) { df[xc][q] = lo[q]; df[xc][q + 4] = hi[q]; }
        }
        #pragma unroll
        for (int wr = 0; wr < 3; ++wr)
            #pragma unroll
            for (int xc = 0; xc < 3; ++xc)
                acc2[wr][xc] = __builtin_amdgcn_mfma_f32_16x16x32_bf16(wf[wr], df[xc], acc2[wr][xc], 0, 0, 0);
    }
    __syncthreads();   // B4: all sD reads done -> region reusable for sF

    // ---------------- epilogue: pack out tile into sF [96][87] fp32 ----------------
    #pragma unroll
    for (int wr = 0; wr < 3; ++wr) {
        const int jb = j0 + 16 * wr + lk * 4;
        float bj[4];
        if (jb + 3 < NN) {
            f32x4u t = *(const f32x4u*)(bias + jb);
            bj[0] = t.x; bj[1] = t.y; bj[2] = t.z; bj[3] = t.w;
        } else {
            #pragma unroll
            for (int q = 0; q < 4; ++q) bj[q] = (jb + q < NN) ? bias[jb + q] : 0.f;
        }
        #pragma unroll
        for (int xc = 0; xc < 3; ++xc) {
            const int i = i0 + 16 * xc + l15;   // rows >=87 land in sF pad rows, never copied
            #pragma unroll
            for (int q = 0; q < 4; ++q) {
                const int j = jb + q;
                if (j < NN) sF[i * NN + j] = acc2[wr][xc][q] + bj[q];
            }
        }
    }
    __syncthreads();   // B5: sF complete

    // ---------------- copy-out: contiguous, alignment-fixed dwordx4 ----------------
    {
        float* __restrict__ gb = out + (size_t)b * NN2;
        const int s = (4 - ((b * NN2) & 3)) & 3;
        if (tid < s) gb[tid] = sF[tid];
        const int C = (NN2 - s) >> 2;
        for (int m = tid; m < C; m += NT) {
            const int n = s + 4 * m;
            f32x4 v;
            v.x = sF[n]; v.y = sF[n + 1]; v.z = sF[n + 2]; v.w = sF[n + 3];
            *(f32x4*)(gb + n) = v;
        }
        const int tl = s + 4 * C;
        if (tid < NN2 - tl) gb[tl + tid] = sF[tl + tid];
    }
}

extern "C" void kernel_launch(void* const* d_in, const int* in_sizes, int n_in,
                              void* d_out, int out_size, void* d_ws, size_t ws_size,
                              hipStream_t stream)
{
    const float* x     = (const float*)d_in[0];
    const float* evals = (const float*)d_in[1];
    const float* evecs = (const float*)d_in[2];
    const float* dtime = (const float*)d_in[3];
    const float* W     = (const float*)d_in[4];
    const float* bias  = (const float*)d_in[5];
    float* out = (float*)d_out;

    const int B = in_sizes[1] / NN;   // evals is (B, 87)

    if (ws_size >= (size_t)WS_NEED) {
        short* wp = (short*)d_ws;
        prep<<<(2 * PANEL + NT - 1) / NT, NT, 0, stream>>>(W, wp);
        fused<true><<<dim3(B), dim3(NT), 0, stream>>>(x, evals, evecs, dtime, W, bias, wp, out);
    } else {
        fused<false><<<dim3(B), dim3(NT), 0, stream>>>(x, evals, evecs, dtime, W, bias, nullptr, out);
    }
}